// Round 6
// baseline (206.427 us; speedup 1.0000x reference)
//
#include <hip/hip_runtime.h>
#include <stdint.h>

#define S_LEN 3072
#define DIM   1536
#define NH    12
#define HD    128
#define QKV_N 4608   // 3*DIM

typedef unsigned short u16;
typedef __bf16 bf16x8 __attribute__((ext_vector_type(8)));
typedef float  f32x4  __attribute__((ext_vector_type(4)));
typedef u16    u16x8  __attribute__((ext_vector_type(8)));

#define AS1 __attribute__((address_space(1)))
#define AS3 __attribute__((address_space(3)))
// async global->LDS, 16B per lane; dest must be wave-uniform base + lane*16
#define GLL16(g, l) __builtin_amdgcn_global_load_lds((AS1 void*)(g), (AS3 void*)(l), 16, 0, 0)

__device__ __forceinline__ u16 f2bf(float f) {
  unsigned u = __float_as_uint(f);
  u = (u + 0x7fffu + ((u >> 16) & 1u)) >> 16;   // RNE
  return (u16)u;
}
__device__ __forceinline__ float bf2f(u16 b) {
  return __uint_as_float(((unsigned)b) << 16);
}

// ---------------- fused fp32 -> bf16 convert (3 tensors, one launch) ----------
__global__ __launch_bounds__(256) void cvt_bf16_3(const float* __restrict__ in0, u16* __restrict__ out0, int n0,
                                                  const float* __restrict__ in1, u16* __restrict__ out1, int n1,
                                                  const float* __restrict__ in2, u16* __restrict__ out2, int n2) {
  int total = n0 + n1 + n2;
  int stride = gridDim.x * blockDim.x;
  for (int i = blockIdx.x * blockDim.x + threadIdx.x; i < total; i += stride) {
    const float* src; u16* dst; int j;
    if (i < n0)           { src = in0; dst = out0; j = i; }
    else if (i < n0 + n1) { src = in1; dst = out1; j = i - n0; }
    else                  { src = in2; dst = out2; j = i - n0 - n1; }
    float4 v = ((const float4*)src)[j];
    ushort4 o;
    o.x = f2bf(v.x); o.y = f2bf(v.y); o.z = f2bf(v.z); o.w = f2bf(v.w);
    ((ushort4*)dst)[j] = o;
  }
}

// ================= 256x256 8-phase GEMM: C = A[M][K] * B[N][K]^T + bias =========
__device__ __forceinline__ bf16x8 frag2(const u16* region, int row, int ch) {
  int L = row >> 1;
  int slot = ((ch + ((row & 1) << 2)) ^ L) & 7;
  return *(const bf16x8*)(region + L * 64 + slot * 8);
}

__global__ __launch_bounds__(512, 2) void gemm_bt_256(const u16* __restrict__ A,
                                                      const u16* __restrict__ B,
                                                      const float* __restrict__ bias,
                                                      u16* __restrict__ Cout,
                                                      int M, int N, int K) {
  __shared__ __attribute__((aligned(16))) u16 lds[8 * 8192];  // 128 KiB

  const int t = threadIdx.x;
  const int l = t & 63;
  const int w = t >> 6;          // 0..7
  const int wm = w >> 2;         // 0..1  (128 rows)
  const int wn = w & 3;          // 0..3  (64 cols)
  const int lr = l & 15;         // frag row lane
  const int lc = l >> 4;         // frag k-chunk (0..3)

  // bijective XCD swizzle over 1D grid
  const int nbx = N >> 8;
  const int nwg = gridDim.x;
  const int q = nwg >> 3, r = nwg & 7;
  const int xcd = blockIdx.x & 7, rest = blockIdx.x >> 3;
  const int wgid = (xcd < r ? xcd * (q + 1) : r * (q + 1) + (xcd - r) * q) + rest;
  const int m0 = (wgid / nbx) * 256;
  const int n0 = (wgid % nbx) * 256;

  const int nk = K >> 6;

  f32x4 acc[8][4];
  #pragma unroll
  for (int i = 0; i < 8; ++i)
    #pragma unroll
    for (int j = 0; j < 4; ++j) acc[i][j] = f32x4{0.f, 0.f, 0.f, 0.f};

  auto stage_half = [&](int buf, int ks, int ab, int kt) {
    const u16* base = ab ? B : A;
    const int x0 = ab ? n0 : m0;
    u16* dst = lds + (((buf << 2) | (ks << 1) | ab) * 8192);
    #pragma unroll
    for (int i = 0; i < 2; ++i) {
      int C = t + i * 512;
      int L = C >> 3, s = C & 7;
      int u = s ^ (L & 7);
      int row = 2 * L + (u >> 2), ch = u & 3;
      const u16* src = base + (size_t)(x0 + row) * K + kt * 64 + ks * 32 + ch * 8;
      GLL16(src, dst + C * 8);
    }
  };

  // prologue: tile0 all 4 halves + tile1 H1,H2; vmcnt(4) -> tile0 landed
  stage_half(0, 0, 0, 0); stage_half(0, 0, 1, 0);
  stage_half(0, 1, 0, 0); stage_half(0, 1, 1, 0);
  if (nk > 1) { stage_half(1, 0, 0, 1); stage_half(1, 0, 1, 1); }
  asm volatile("s_waitcnt vmcnt(4)" ::: "memory");
  __builtin_amdgcn_s_barrier();

  for (int kt = 0; kt < nk; ++kt) {
    const int buf = kt & 1, nbuf = buf ^ 1;
    const bool st1 = (kt + 1 < nk);
    const bool st2 = (kt + 2 < nk);

    const u16* A0 = lds + (((buf << 2) | 0) * 8192);
    const u16* B0 = lds + (((buf << 2) | 1) * 8192);
    const u16* A1 = lds + (((buf << 2) | 2) * 8192);
    const u16* B1 = lds + (((buf << 2) | 3) * 8192);

    bf16x8 bfrag[4], afr[4];

    // ---- ph0 ----
    #pragma unroll
    for (int ni = 0; ni < 4; ++ni) bfrag[ni] = frag2(B0, wn * 64 + ni * 16 + lr, lc);
    #pragma unroll
    for (int mi = 0; mi < 4; ++mi) afr[mi] = frag2(A0, wm * 128 + mi * 16 + lr, lc);
    if (st1) stage_half(nbuf, 1, 0, kt + 1);
    __builtin_amdgcn_s_barrier();
    __builtin_amdgcn_s_setprio(1);
    #pragma unroll
    for (int mi = 0; mi < 4; ++mi)
      #pragma unroll
      for (int ni = 0; ni < 4; ++ni)
        acc[mi][ni] = __builtin_amdgcn_mfma_f32_16x16x32_bf16(afr[mi], bfrag[ni],
                                                              acc[mi][ni], 0, 0, 0);
    __builtin_amdgcn_s_setprio(0);
    __builtin_amdgcn_s_barrier();

    // ---- ph1 ----
    #pragma unroll
    for (int mi = 0; mi < 4; ++mi) afr[mi] = frag2(A0, wm * 128 + 64 + mi * 16 + lr, lc);
    if (st1) stage_half(nbuf, 1, 1, kt + 1);
    __builtin_amdgcn_s_barrier();
    __builtin_amdgcn_s_setprio(1);
    #pragma unroll
    for (int mi = 0; mi < 4; ++mi)
      #pragma unroll
      for (int ni = 0; ni < 4; ++ni)
        acc[4 + mi][ni] = __builtin_amdgcn_mfma_f32_16x16x32_bf16(afr[mi], bfrag[ni],
                                                                  acc[4 + mi][ni], 0, 0, 0);
    __builtin_amdgcn_s_setprio(0);
    __builtin_amdgcn_s_barrier();

    // ---- ph2 ----
    #pragma unroll
    for (int ni = 0; ni < 4; ++ni) bfrag[ni] = frag2(B1, wn * 64 + ni * 16 + lr, lc);
    #pragma unroll
    for (int mi = 0; mi < 4; ++mi) afr[mi] = frag2(A1, wm * 128 + mi * 16 + lr, lc);
    if (st2) stage_half(buf, 0, 0, kt + 2);
    __builtin_amdgcn_s_barrier();
    __builtin_amdgcn_s_setprio(1);
    #pragma unroll
    for (int mi = 0; mi < 4; ++mi)
      #pragma unroll
      for (int ni = 0; ni < 4; ++ni)
        acc[mi][ni] = __builtin_amdgcn_mfma_f32_16x16x32_bf16(afr[mi], bfrag[ni],
                                                              acc[mi][ni], 0, 0, 0);
    __builtin_amdgcn_s_setprio(0);
    __builtin_amdgcn_s_barrier();

    // ---- ph3 ----
    #pragma unroll
    for (int mi = 0; mi < 4; ++mi) afr[mi] = frag2(A1, wm * 128 + 64 + mi * 16 + lr, lc);
    if (st2) {
      stage_half(buf, 0, 1, kt + 2);
      asm volatile("s_waitcnt vmcnt(4)" ::: "memory");
    } else if (st1) {
      asm volatile("s_waitcnt vmcnt(0)" ::: "memory");
    }
    __builtin_amdgcn_s_barrier();
    __builtin_amdgcn_s_setprio(1);
    #pragma unroll
    for (int mi = 0; mi < 4; ++mi)
      #pragma unroll
      for (int ni = 0; ni < 4; ++ni)
        acc[4 + mi][ni] = __builtin_amdgcn_mfma_f32_16x16x32_bf16(afr[mi], bfrag[ni],
                                                                  acc[4 + mi][ni], 0, 0, 0);
    __builtin_amdgcn_s_setprio(0);
    __builtin_amdgcn_s_barrier();
  }

  // ---- epilogue: stage C in LDS (XOR-swizzled), store coalesced ----
  {
    float bv[4];
    #pragma unroll
    for (int ni = 0; ni < 4; ++ni)
      bv[ni] = bias ? bias[n0 + wn * 64 + ni * 16 + lr] : 0.f;
    #pragma unroll
    for (int mi = 0; mi < 8; ++mi) {
      int row = wm * 128 + mi * 16 + lc * 4;
      #pragma unroll
      for (int ni = 0; ni < 4; ++ni) {
        int scol = (wn * 64 + ni * 16 + lr) ^ (lc << 4);
        #pragma unroll
        for (int rr = 0; rr < 4; ++rr)
          lds[(row + rr) * 256 + scol] = f2bf(acc[mi][ni][rr] + bv[ni]);
      }
    }
    __syncthreads();
    #pragma unroll
    for (int i = 0; i < 16; ++i) {
      int id = i * 512 + t;
      int row = id >> 5, c16 = id & 31;
      int s = (row >> 2) & 3;
      u16x8 v = *(const u16x8*)(lds + row * 256 + ((c16 * 8) ^ (s << 4)));
      *(u16x8*)(Cout + (size_t)(m0 + row) * N + n0 + c16 * 8) = v;
    }
  }
}

// ---------------- GEMM: C[M][N] = A[M][K] * B[N][K]^T (128x128, for GEMM2) ------
__device__ __forceinline__ bf16x8 lds_frag(const u16* base, int row, int ch) {
  return *(const bf16x8*)(base + row * 64 + ((ch ^ row) & 7) * 8);
}

template <bool BIAS, bool OUTF32>
__global__ __launch_bounds__(256) void gemm_bt(const u16* __restrict__ A,
                                               const u16* __restrict__ B,
                                               const float* __restrict__ bias,
                                               void* __restrict__ Cout,
                                               int M, int N, int K) {
  __shared__ u16 Asm[128 * 64];
  __shared__ u16 Bsm[128 * 64];
  const int t = threadIdx.x;
  const int l = t & 63;
  const int w = t >> 6;
  const int wm = w >> 1, wn = w & 1;
  const int m0 = blockIdx.y * 128, n0 = blockIdx.x * 128;

  f32x4 acc[4][4];
  #pragma unroll
  for (int i = 0; i < 4; ++i)
    #pragma unroll
    for (int j = 0; j < 4; ++j) acc[i][j] = f32x4{0.f, 0.f, 0.f, 0.f};

  for (int k0 = 0; k0 < K; k0 += 64) {
    __syncthreads();
    #pragma unroll
    for (int r4 = 0; r4 < 4; ++r4) {
      int C = t + r4 * 256;
      int row = C >> 3, ch = C & 7;
      int sch = (ch ^ row) & 7;
      GLL16(A + (size_t)(m0 + row) * K + k0 + sch * 8, Asm + (size_t)C * 8);
      GLL16(B + (size_t)(n0 + row) * K + k0 + sch * 8, Bsm + (size_t)C * 8);
    }
    __syncthreads();
    #pragma unroll
    for (int ks = 0; ks < 2; ++ks) {
      bf16x8 af[4], bfr[4];
      #pragma unroll
      for (int mi = 0; mi < 4; ++mi)
        af[mi] = lds_frag(Asm, wm * 64 + mi * 16 + (l & 15), ks * 4 + (l >> 4));
      #pragma unroll
      for (int ni = 0; ni < 4; ++ni)
        bfr[ni] = lds_frag(Bsm, wn * 64 + ni * 16 + (l & 15), ks * 4 + (l >> 4));
      #pragma unroll
      for (int mi = 0; mi < 4; ++mi)
        #pragma unroll
        for (int ni = 0; ni < 4; ++ni)
          acc[mi][ni] = __builtin_amdgcn_mfma_f32_16x16x32_bf16(af[mi], bfr[ni],
                                                                acc[mi][ni], 0, 0, 0);
    }
  }

  #pragma unroll
  for (int ni = 0; ni < 4; ++ni) {
    int col = n0 + wn * 64 + ni * 16 + (l & 15);
    float bv = 0.f;
    if (BIAS) bv = bias[col];
    #pragma unroll
    for (int mi = 0; mi < 4; ++mi) {
      int rbase = m0 + wm * 64 + mi * 16 + ((l >> 4) << 2);
      #pragma unroll
      for (int rr = 0; rr < 4; ++rr) {
        float v = acc[mi][ni][rr] + bv;
        if (OUTF32)
          ((float*)Cout)[(size_t)(rbase + rr) * N + col] = v;
        else
          ((u16*)Cout)[(size_t)(rbase + rr) * N + col] = f2bf(v);
      }
    }
  }
}

// ---------------- RoPE + repack q/k, transpose v (vectorized) ----------------
__global__ __launch_bounds__(256) void rope_pack(const u16* __restrict__ QKV,
                                                 const float* __restrict__ cosb,
                                                 const float* __restrict__ sinb,
                                                 u16* __restrict__ Qp,
                                                 u16* __restrict__ Kp,
                                                 u16* __restrict__ Vt) {
  __shared__ u16 vtile[64][128];
  const int t = threadIdx.x;
  const int s0 = blockIdx.x * 64;
  const int h = blockIdx.y;

  const int srow = s0 + (t >> 2);
  const int d0 = (t & 3) * 16;
  const u16* qkvrow = QKV + (size_t)srow * QKV_N + h * HD;
  const float qscale = 0.08838834764831845f * 1.4426950408889634f; // HD^-0.5 * log2(e)

  float cl[16], chh[16], sl[16], shh[16];
  #pragma unroll
  for (int g = 0; g < 4; ++g) {
    *(float4*)(cl + 4 * g)  = *(const float4*)(cosb + srow * HD + d0 + 4 * g);
    *(float4*)(chh + 4 * g) = *(const float4*)(cosb + srow * HD + d0 + 64 + 4 * g);
    *(float4*)(sl + 4 * g)  = *(const float4*)(sinb + srow * HD + d0 + 4 * g);
    *(float4*)(shh + 4 * g) = *(const float4*)(sinb + srow * HD + d0 + 64 + 4 * g);
  }

  #pragma unroll
  for (int which = 0; which < 2; ++which) {
    const u16* src = qkvrow + which * DIM;
    u16* dst = (which ? Kp : Qp) + ((size_t)h * S_LEN + srow) * HD;
    const float sc = which ? 1.f : qscale;
    u16x8 xl0 = *(const u16x8*)(src + d0);
    u16x8 xl1 = *(const u16x8*)(src + d0 + 8);
    u16x8 xh0 = *(const u16x8*)(src + d0 + 64);
    u16x8 xh1 = *(const u16x8*)(src + d0 + 72);
    u16x8 o0, o1, o2, o3;
    #pragma unroll
    for (int j = 0; j < 8; ++j) {
      float xlo = bf2f(xl0[j]), xhi = bf2f(xh0[j]);
      o0[j] = f2bf((xlo * cl[j] - xhi * sl[j]) * sc);
      o2[j] = f2bf((xhi * chh[j] + xlo * shh[j]) * sc);
      float xlo2 = bf2f(xl1[j]), xhi2 = bf2f(xh1[j]);
      o1[j] = f2bf((xlo2 * cl[j + 8] - xhi2 * sl[j + 8]) * sc);
      o3[j] = f2bf((xhi2 * chh[j + 8] + xlo2 * shh[j + 8]) * sc);
    }
    *(u16x8*)(dst + d0)      = o0;
    *(u16x8*)(dst + d0 + 8)  = o1;
    *(u16x8*)(dst + d0 + 64) = o2;
    *(u16x8*)(dst + d0 + 72) = o3;
  }

  #pragma unroll
  for (int r4 = 0; r4 < 4; ++r4) {
    int C = t + r4 * 256;
    int row = C >> 4, ch = C & 15;
    *(uint4*)(&vtile[row][ch * 8]) =
        *(const uint4*)(QKV + (size_t)(s0 + row) * QKV_N + 2 * DIM + h * HD + ch * 8);
  }
  __syncthreads();
  const int d = t >> 1;
  const int sc0 = (t & 1) * 32;
  u16* vdst = Vt + ((size_t)h * HD + d) * S_LEN + s0 + sc0;
  #pragma unroll
  for (int j = 0; j < 32; j += 8) {
    u16x8 v;
    #pragma unroll
    for (int e = 0; e < 8; ++e) v[e] = vtile[sc0 + j + e][d];
    *(u16x8*)(vdst + j) = v;
  }
}

// ------ flash attention: K-dbuf LDS (counted vmcnt), V direct from global/L2 ----
__global__ __launch_bounds__(256) void attn_fwd(const u16* __restrict__ Qp,
                                                const u16* __restrict__ Kp,
                                                const u16* __restrict__ Vt,
                                                const int* __restrict__ cu,
                                                u16* __restrict__ Obf) {
  __shared__ u16 K_lds[2][64 * 128];    // [buf][kv][d], chunk-swizzled (32 KiB)
  __shared__ u16 P_lds[4][16 * 76];     // per-wave P, stride 76 (bank-disjoint rows)

  const int t = threadIdx.x;
  const int l = t & 63;
  const int w = t >> 6;
  const int lr = l & 15;
  const int lq = l >> 4;
  const int q0 = blockIdx.x * 64;
  const int h = blockIdx.y;

  int cs = 0, ce = S_LEN;
  #pragma unroll
  for (int b = 0; b < 4; ++b) {
    int lo = cu[b], hi = cu[b + 1];
    if (q0 >= lo && q0 < hi) { cs = lo; ce = hi; }
  }

  const int qrow = q0 + w * 16 + lr;
  bf16x8 qf[4];
  const u16* qptr = Qp + ((size_t)h * S_LEN + qrow) * HD + lq * 8;
  #pragma unroll
  for (int ks = 0; ks < 4; ++ks) qf[ks] = *(const bf16x8*)(qptr + ks * 32);

  const u16* vhead = Vt + (size_t)h * HD * S_LEN;

  f32x4 acc_o[8];
  #pragma unroll
  for (int i = 0; i < 8; ++i) acc_o[i] = f32x4{0.f, 0.f, 0.f, 0.f};
  float m_run[4], l_run[4];
  #pragma unroll
  for (int r = 0; r < 4; ++r) { m_run[r] = -1e30f; l_run[r] = 0.f; }

  // stage K tile at kv0 into buffer c: 4 GLL16 per thread
  auto stage = [&](int c, int kv0) {
    const u16* kbase = Kp + ((size_t)h * S_LEN + kv0) * HD;
    #pragma unroll
    for (int r4 = 0; r4 < 4; ++r4) {
      int C = t + r4 * 256;
      int row = C >> 4, ch = C & 15;
      int sch = (ch & 8) | ((ch ^ row) & 7);
      GLL16(kbase + row * HD + sch * 8, &K_lds[c][0] + (size_t)C * 8);
    }
  };

  const int nt = (ce - cs) >> 6;
  stage(0, cs);

  for (int it = 0; it < nt; ++it) {
    const int cur = it & 1;
    const int kv0 = cs + it * 64;
    __builtin_amdgcn_s_barrier();          // all waves done reading buf cur^1
    if (it + 1 < nt) {
      stage(cur ^ 1, kv0 + 64);            // prefetch next K tile
      asm volatile("s_waitcnt vmcnt(4)" ::: "memory");   // cur's 4 landed
    } else {
      asm volatile("s_waitcnt vmcnt(0)" ::: "memory");
    }
    __builtin_amdgcn_s_barrier();          // everyone's cur loads landed

    const u16* kb = &K_lds[cur][0];

    f32x4 s_acc[4];
    __builtin_amdgcn_s_setprio(1);
    #pragma unroll
    for (int nf = 0; nf < 4; ++nf) {
      s_acc[nf] = f32x4{0.f, 0.f, 0.f, 0.f};
      int kcol = nf * 16 + lr;
      #pragma unroll
      for (int ks = 0; ks < 4; ++ks) {
        int ch = ks * 4 + lq;
        int sch = (ch & 8) | ((ch ^ kcol) & 7);
        bf16x8 kf = *(const bf16x8*)(kb + kcol * 128 + sch * 8);
        s_acc[nf] = __builtin_amdgcn_mfma_f32_16x16x32_bf16(qf[ks], kf, s_acc[nf], 0, 0, 0);
      }
    }
    __builtin_amdgcn_s_setprio(0);

    float p[4][4], alpha[4];
    #pragma unroll
    for (int r = 0; r < 4; ++r) {
      float v = fmaxf(fmaxf(s_acc[0][r], s_acc[1][r]), fmaxf(s_acc[2][r], s_acc[3][r]));
      #pragma unroll
      for (int m = 1; m < 16; m <<= 1) v = fmaxf(v, __shfl_xor(v, m, 64));
      float mn = fmaxf(m_run[r], v);
      alpha[r] = __builtin_amdgcn_exp2f(m_run[r] - mn);
      m_run[r] = mn;
      float sum = 0.f;
      #pragma unroll
      for (int nf = 0; nf < 4; ++nf) {
        float pv = __builtin_amdgcn_exp2f(s_acc[nf][r] - mn);
        p[nf][r] = pv;
        sum += pv;
      }
      #pragma unroll
      for (int m = 1; m < 16; m <<= 1) sum += __shfl_xor(sum, m, 64);
      l_run[r] = l_run[r] * alpha[r] + sum;
    }
    #pragma unroll
    for (int onf = 0; onf < 8; ++onf)
      #pragma unroll
      for (int r = 0; r < 4; ++r) acc_o[onf][r] *= alpha[r];

    u16* pl = P_lds[w];
    #pragma unroll
    for (int nf = 0; nf < 4; ++nf)
      #pragma unroll
      for (int r = 0; r < 4; ++r)
        pl[(lq * 4 + r) * 76 + nf * 16 + lr] = f2bf(p[nf][r]);

    // O += P V   (V B-fragments straight from global Vt[h][d][s] — L2-resident)
    __builtin_amdgcn_s_setprio(1);
    #pragma unroll
    for (int ks = 0; ks < 2; ++ks) {
      bf16x8 pa = *(const bf16x8*)(pl + lr * 76 + ks * 32 + lq * 8);
      #pragma unroll
      for (int onf = 0; onf < 8; ++onf) {
        int d = onf * 16 + lr;
        int ch = ks * 4 + lq;
        bf16x8 vf = *(const bf16x8*)(vhead + (size_t)d * S_LEN + kv0 + ch * 8);
        acc_o[onf] = __builtin_amdgcn_mfma_f32_16x16x32_bf16(pa, vf, acc_o[onf], 0, 0, 0);
      }
    }
    __builtin_amdgcn_s_setprio(0);
  }

  #pragma unroll
  for (int r = 0; r < 4; ++r) {
    float inv = 1.f / l_run[r];
    int srow = q0 + w * 16 + (lq << 2) + r;
    u16* orow = Obf + (size_t)srow * DIM + h * HD + lr;
    #pragma unroll
    for (int onf = 0; onf < 8; ++onf) orow[onf * 16] = f2bf(acc_o[onf][r] * inv);
  }
}

extern "C" void kernel_launch(void* const* d_in, const int* in_sizes, int n_in,
                              void* d_out, int out_size, void* d_ws, size_t ws_size,
                              hipStream_t stream) {
  const float* hidden = (const float*)d_in[0];
  const float* cosb   = (const float*)d_in[1];
  const float* sinb   = (const float*)d_in[2];
  const float* qkv_w  = (const float*)d_in[3];
  const float* qkv_b  = (const float*)d_in[4];
  const float* proj_w = (const float*)d_in[5];
  const int*   cu     = (const int*)d_in[6];

  u16* Hbf   = (u16*)d_ws;
  u16* Wqkv  = Hbf   + (size_t)S_LEN * DIM;
  u16* Wproj = Wqkv  + (size_t)QKV_N * DIM;
  u16* QKVbf = Wproj + (size_t)DIM * DIM;
  u16* Kp    = QKVbf + (size_t)S_LEN * QKV_N;
  u16* Vt    = Kp    + (size_t)NH * S_LEN * HD;
  u16* Qp    = Wqkv;  // reuse: Wqkv dead after GEMM1
  u16* Abf   = Hbf;   // reuse: Hbf dead after GEMM1

  cvt_bf16_3<<<2048, 256, 0, stream>>>(hidden, Hbf, S_LEN * DIM / 4,
                                       qkv_w, Wqkv, QKV_N * DIM / 4,
                                       proj_w, Wproj, DIM * DIM / 4);

  gemm_bt_256<<<(S_LEN / 256) * (QKV_N / 256), 512, 0, stream>>>(
      Hbf, Wqkv, qkv_b, QKVbf, S_LEN, QKV_N, DIM);

  rope_pack<<<dim3(S_LEN / 64, NH), 256, 0, stream>>>(QKVbf, cosb, sinb, Qp, Kp, Vt);

  attn_fwd<<<dim3(S_LEN / 64, NH), 256, 0, stream>>>(Qp, Kp, Vt, cu, Abf);

  gemm_bt<false, true><<<dim3(DIM / 128, S_LEN / 128), 256, 0, stream>>>(
      Abf, Wproj, nullptr, d_out, S_LEN, DIM, DIM);
}

// Round 7
// 154.781 us; speedup vs baseline: 1.3337x; 1.3337x over previous
//
#include <hip/hip_runtime.h>
#include <stdint.h>

#define S_LEN 3072
#define DIM   1536
#define NH    12
#define HD    128
#define QKV_N 4608   // 3*DIM

typedef unsigned short u16;
typedef __bf16 bf16x8 __attribute__((ext_vector_type(8)));
typedef float  f32x4  __attribute__((ext_vector_type(4)));
typedef u16    u16x8  __attribute__((ext_vector_type(8)));
typedef u16    u16x4  __attribute__((ext_vector_type(4)));

#define AS1 __attribute__((address_space(1)))
#define AS3 __attribute__((address_space(3)))
// async global->LDS, 16B per lane; dest must be wave-uniform base + lane*16
#define GLL16(g, l) __builtin_amdgcn_global_load_lds((AS1 void*)(g), (AS3 void*)(l), 16, 0, 0)

__device__ __forceinline__ u16 f2bf(float f) {
  unsigned u = __float_as_uint(f);
  u = (u + 0x7fffu + ((u >> 16) & 1u)) >> 16;   // RNE
  return (u16)u;
}
__device__ __forceinline__ float bf2f(u16 b) {
  return __uint_as_float(((unsigned)b) << 16);
}

// ---------------- fused fp32 -> bf16 convert (3 tensors, one launch) ----------
__global__ __launch_bounds__(256) void cvt_bf16_3(const float* __restrict__ in0, u16* __restrict__ out0, int n0,
                                                  const float* __restrict__ in1, u16* __restrict__ out1, int n1,
                                                  const float* __restrict__ in2, u16* __restrict__ out2, int n2) {
  int total = n0 + n1 + n2;
  int stride = gridDim.x * blockDim.x;
  for (int i = blockIdx.x * blockDim.x + threadIdx.x; i < total; i += stride) {
    const float* src; u16* dst; int j;
    if (i < n0)           { src = in0; dst = out0; j = i; }
    else if (i < n0 + n1) { src = in1; dst = out1; j = i - n0; }
    else                  { src = in2; dst = out2; j = i - n0 - n1; }
    float4 v = ((const float4*)src)[j];
    ushort4 o;
    o.x = f2bf(v.x); o.y = f2bf(v.y); o.z = f2bf(v.z); o.w = f2bf(v.w);
    ((ushort4*)dst)[j] = o;
  }
}

// ================= 256x256 8-phase GEMM: C = A[M][K] * B[N][K]^T + bias =========
__device__ __forceinline__ bf16x8 frag2(const u16* region, int row, int ch) {
  int L = row >> 1;
  int slot = ((ch + ((row & 1) << 2)) ^ L) & 7;
  return *(const bf16x8*)(region + L * 64 + slot * 8);
}

__global__ __launch_bounds__(512, 2) void gemm_bt_256(const u16* __restrict__ A,
                                                      const u16* __restrict__ B,
                                                      const float* __restrict__ bias,
                                                      u16* __restrict__ Cout,
                                                      int M, int N, int K) {
  __shared__ __attribute__((aligned(16))) u16 lds[8 * 8192];  // 128 KiB

  const int t = threadIdx.x;
  const int l = t & 63;
  const int w = t >> 6;          // 0..7
  const int wm = w >> 2;         // 0..1  (128 rows)
  const int wn = w & 3;          // 0..3  (64 cols)
  const int lr = l & 15;         // frag row lane
  const int lc = l >> 4;         // frag k-chunk (0..3)

  // bijective XCD swizzle over 1D grid
  const int nbx = N >> 8;
  const int nwg = gridDim.x;
  const int q = nwg >> 3, r = nwg & 7;
  const int xcd = blockIdx.x & 7, rest = blockIdx.x >> 3;
  const int wgid = (xcd < r ? xcd * (q + 1) : r * (q + 1) + (xcd - r) * q) + rest;
  const int m0 = (wgid / nbx) * 256;
  const int n0 = (wgid % nbx) * 256;

  const int nk = K >> 6;

  f32x4 acc[8][4];
  #pragma unroll
  for (int i = 0; i < 8; ++i)
    #pragma unroll
    for (int j = 0; j < 4; ++j) acc[i][j] = f32x4{0.f, 0.f, 0.f, 0.f};

  auto stage_half = [&](int buf, int ks, int ab, int kt) {
    const u16* base = ab ? B : A;
    const int x0 = ab ? n0 : m0;
    u16* dst = lds + (((buf << 2) | (ks << 1) | ab) * 8192);
    #pragma unroll
    for (int i = 0; i < 2; ++i) {
      int C = t + i * 512;
      int L = C >> 3, s = C & 7;
      int u = s ^ (L & 7);
      int row = 2 * L + (u >> 2), ch = u & 3;
      const u16* src = base + (size_t)(x0 + row) * K + kt * 64 + ks * 32 + ch * 8;
      GLL16(src, dst + C * 8);
    }
  };

  // prologue: tile0 all 4 halves + tile1 H1,H2; vmcnt(4) -> tile0 landed
  stage_half(0, 0, 0, 0); stage_half(0, 0, 1, 0);
  stage_half(0, 1, 0, 0); stage_half(0, 1, 1, 0);
  if (nk > 1) { stage_half(1, 0, 0, 1); stage_half(1, 0, 1, 1); }
  asm volatile("s_waitcnt vmcnt(4)" ::: "memory");
  __builtin_amdgcn_s_barrier();

  for (int kt = 0; kt < nk; ++kt) {
    const int buf = kt & 1, nbuf = buf ^ 1;
    const bool st1 = (kt + 1 < nk);
    const bool st2 = (kt + 2 < nk);

    const u16* A0 = lds + (((buf << 2) | 0) * 8192);
    const u16* B0 = lds + (((buf << 2) | 1) * 8192);
    const u16* A1 = lds + (((buf << 2) | 2) * 8192);
    const u16* B1 = lds + (((buf << 2) | 3) * 8192);

    bf16x8 bfrag[4], afr[4];

    // ---- ph0 ----
    #pragma unroll
    for (int ni = 0; ni < 4; ++ni) bfrag[ni] = frag2(B0, wn * 64 + ni * 16 + lr, lc);
    #pragma unroll
    for (int mi = 0; mi < 4; ++mi) afr[mi] = frag2(A0, wm * 128 + mi * 16 + lr, lc);
    if (st1) stage_half(nbuf, 1, 0, kt + 1);
    __builtin_amdgcn_s_barrier();
    __builtin_amdgcn_s_setprio(1);
    #pragma unroll
    for (int mi = 0; mi < 4; ++mi)
      #pragma unroll
      for (int ni = 0; ni < 4; ++ni)
        acc[mi][ni] = __builtin_amdgcn_mfma_f32_16x16x32_bf16(afr[mi], bfrag[ni],
                                                              acc[mi][ni], 0, 0, 0);
    __builtin_amdgcn_s_setprio(0);
    __builtin_amdgcn_s_barrier();

    // ---- ph1 ----
    #pragma unroll
    for (int mi = 0; mi < 4; ++mi) afr[mi] = frag2(A0, wm * 128 + 64 + mi * 16 + lr, lc);
    if (st1) stage_half(nbuf, 1, 1, kt + 1);
    __builtin_amdgcn_s_barrier();
    __builtin_amdgcn_s_setprio(1);
    #pragma unroll
    for (int mi = 0; mi < 4; ++mi)
      #pragma unroll
      for (int ni = 0; ni < 4; ++ni)
        acc[4 + mi][ni] = __builtin_amdgcn_mfma_f32_16x16x32_bf16(afr[mi], bfrag[ni],
                                                                  acc[4 + mi][ni], 0, 0, 0);
    __builtin_amdgcn_s_setprio(0);
    __builtin_amdgcn_s_barrier();

    // ---- ph2 ----
    #pragma unroll
    for (int ni = 0; ni < 4; ++ni) bfrag[ni] = frag2(B1, wn * 64 + ni * 16 + lr, lc);
    #pragma unroll
    for (int mi = 0; mi < 4; ++mi) afr[mi] = frag2(A1, wm * 128 + mi * 16 + lr, lc);
    if (st2) stage_half(buf, 0, 0, kt + 2);
    __builtin_amdgcn_s_barrier();
    __builtin_amdgcn_s_setprio(1);
    #pragma unroll
    for (int mi = 0; mi < 4; ++mi)
      #pragma unroll
      for (int ni = 0; ni < 4; ++ni)
        acc[mi][ni] = __builtin_amdgcn_mfma_f32_16x16x32_bf16(afr[mi], bfrag[ni],
                                                              acc[mi][ni], 0, 0, 0);
    __builtin_amdgcn_s_setprio(0);
    __builtin_amdgcn_s_barrier();

    // ---- ph3 ----
    #pragma unroll
    for (int mi = 0; mi < 4; ++mi) afr[mi] = frag2(A1, wm * 128 + 64 + mi * 16 + lr, lc);
    if (st2) {
      stage_half(buf, 0, 1, kt + 2);
      asm volatile("s_waitcnt vmcnt(4)" ::: "memory");
    } else if (st1) {
      asm volatile("s_waitcnt vmcnt(0)" ::: "memory");
    }
    __builtin_amdgcn_s_barrier();
    __builtin_amdgcn_s_setprio(1);
    #pragma unroll
    for (int mi = 0; mi < 4; ++mi)
      #pragma unroll
      for (int ni = 0; ni < 4; ++ni)
        acc[4 + mi][ni] = __builtin_amdgcn_mfma_f32_16x16x32_bf16(afr[mi], bfrag[ni],
                                                                  acc[4 + mi][ni], 0, 0, 0);
    __builtin_amdgcn_s_setprio(0);
    __builtin_amdgcn_s_barrier();
  }

  // ---- epilogue: stage C in LDS (XOR-swizzled), store coalesced ----
  {
    float bv[4];
    #pragma unroll
    for (int ni = 0; ni < 4; ++ni)
      bv[ni] = bias ? bias[n0 + wn * 64 + ni * 16 + lr] : 0.f;
    #pragma unroll
    for (int mi = 0; mi < 8; ++mi) {
      int row = wm * 128 + mi * 16 + lc * 4;
      #pragma unroll
      for (int ni = 0; ni < 4; ++ni) {
        int scol = (wn * 64 + ni * 16 + lr) ^ (lc << 4);
        #pragma unroll
        for (int rr = 0; rr < 4; ++rr)
          lds[(row + rr) * 256 + scol] = f2bf(acc[mi][ni][rr] + bv[ni]);
      }
    }
    __syncthreads();
    #pragma unroll
    for (int i = 0; i < 16; ++i) {
      int id = i * 512 + t;
      int row = id >> 5, c16 = id & 31;
      int s = (row >> 2) & 3;
      u16x8 v = *(const u16x8*)(lds + row * 256 + ((c16 * 8) ^ (s << 4)));
      *(u16x8*)(Cout + (size_t)(m0 + row) * N + n0 + c16 * 8) = v;
    }
  }
}

// ---------------- GEMM: C[M][N] = A[M][K] * B[N][K]^T (128x128, for GEMM2) ------
__device__ __forceinline__ bf16x8 lds_frag(const u16* base, int row, int ch) {
  return *(const bf16x8*)(base + row * 64 + ((ch ^ row) & 7) * 8);
}

template <bool BIAS, bool OUTF32>
__global__ __launch_bounds__(256) void gemm_bt(const u16* __restrict__ A,
                                               const u16* __restrict__ B,
                                               const float* __restrict__ bias,
                                               void* __restrict__ Cout,
                                               int M, int N, int K) {
  __shared__ u16 Asm[128 * 64];
  __shared__ u16 Bsm[128 * 64];
  const int t = threadIdx.x;
  const int l = t & 63;
  const int w = t >> 6;
  const int wm = w >> 1, wn = w & 1;
  const int m0 = blockIdx.y * 128, n0 = blockIdx.x * 128;

  f32x4 acc[4][4];
  #pragma unroll
  for (int i = 0; i < 4; ++i)
    #pragma unroll
    for (int j = 0; j < 4; ++j) acc[i][j] = f32x4{0.f, 0.f, 0.f, 0.f};

  for (int k0 = 0; k0 < K; k0 += 64) {
    __syncthreads();
    #pragma unroll
    for (int r4 = 0; r4 < 4; ++r4) {
      int C = t + r4 * 256;
      int row = C >> 3, ch = C & 7;
      int sch = (ch ^ row) & 7;
      GLL16(A + (size_t)(m0 + row) * K + k0 + sch * 8, Asm + (size_t)C * 8);
      GLL16(B + (size_t)(n0 + row) * K + k0 + sch * 8, Bsm + (size_t)C * 8);
    }
    __syncthreads();
    #pragma unroll
    for (int ks = 0; ks < 2; ++ks) {
      bf16x8 af[4], bfr[4];
      #pragma unroll
      for (int mi = 0; mi < 4; ++mi)
        af[mi] = lds_frag(Asm, wm * 64 + mi * 16 + (l & 15), ks * 4 + (l >> 4));
      #pragma unroll
      for (int ni = 0; ni < 4; ++ni)
        bfr[ni] = lds_frag(Bsm, wn * 64 + ni * 16 + (l & 15), ks * 4 + (l >> 4));
      #pragma unroll
      for (int mi = 0; mi < 4; ++mi)
        #pragma unroll
        for (int ni = 0; ni < 4; ++ni)
          acc[mi][ni] = __builtin_amdgcn_mfma_f32_16x16x32_bf16(af[mi], bfr[ni],
                                                                acc[mi][ni], 0, 0, 0);
    }
  }

  #pragma unroll
  for (int ni = 0; ni < 4; ++ni) {
    int col = n0 + wn * 64 + ni * 16 + (l & 15);
    float bv = 0.f;
    if (BIAS) bv = bias[col];
    #pragma unroll
    for (int mi = 0; mi < 4; ++mi) {
      int rbase = m0 + wm * 64 + mi * 16 + ((l >> 4) << 2);
      #pragma unroll
      for (int rr = 0; rr < 4; ++rr) {
        float v = acc[mi][ni][rr] + bv;
        if (OUTF32)
          ((float*)Cout)[(size_t)(rbase + rr) * N + col] = v;
        else
          ((u16*)Cout)[(size_t)(rbase + rr) * N + col] = f2bf(v);
      }
    }
  }
}

// ---------------- RoPE + repack q/k, transpose v (vectorized) ----------------
__global__ __launch_bounds__(256) void rope_pack(const u16* __restrict__ QKV,
                                                 const float* __restrict__ cosb,
                                                 const float* __restrict__ sinb,
                                                 u16* __restrict__ Qp,
                                                 u16* __restrict__ Kp,
                                                 u16* __restrict__ Vt) {
  __shared__ u16 vtile[64][128];
  const int t = threadIdx.x;
  const int s0 = blockIdx.x * 64;
  const int h = blockIdx.y;

  const int srow = s0 + (t >> 2);
  const int d0 = (t & 3) * 16;
  const u16* qkvrow = QKV + (size_t)srow * QKV_N + h * HD;
  const float qscale = 0.08838834764831845f * 1.4426950408889634f; // HD^-0.5 * log2(e)

  float cl[16], chh[16], sl[16], shh[16];
  #pragma unroll
  for (int g = 0; g < 4; ++g) {
    *(float4*)(cl + 4 * g)  = *(const float4*)(cosb + srow * HD + d0 + 4 * g);
    *(float4*)(chh + 4 * g) = *(const float4*)(cosb + srow * HD + d0 + 64 + 4 * g);
    *(float4*)(sl + 4 * g)  = *(const float4*)(sinb + srow * HD + d0 + 4 * g);
    *(float4*)(shh + 4 * g) = *(const float4*)(sinb + srow * HD + d0 + 64 + 4 * g);
  }

  #pragma unroll
  for (int which = 0; which < 2; ++which) {
    const u16* src = qkvrow + which * DIM;
    u16* dst = (which ? Kp : Qp) + ((size_t)h * S_LEN + srow) * HD;
    const float sc = which ? 1.f : qscale;
    u16x8 xl0 = *(const u16x8*)(src + d0);
    u16x8 xl1 = *(const u16x8*)(src + d0 + 8);
    u16x8 xh0 = *(const u16x8*)(src + d0 + 64);
    u16x8 xh1 = *(const u16x8*)(src + d0 + 72);
    u16x8 o0, o1, o2, o3;
    #pragma unroll
    for (int j = 0; j < 8; ++j) {
      float xlo = bf2f(xl0[j]), xhi = bf2f(xh0[j]);
      o0[j] = f2bf((xlo * cl[j] - xhi * sl[j]) * sc);
      o2[j] = f2bf((xhi * chh[j] + xlo * shh[j]) * sc);
      float xlo2 = bf2f(xl1[j]), xhi2 = bf2f(xh1[j]);
      o1[j] = f2bf((xlo2 * cl[j + 8] - xhi2 * sl[j + 8]) * sc);
      o3[j] = f2bf((xhi2 * chh[j + 8] + xlo2 * shh[j + 8]) * sc);
    }
    *(u16x8*)(dst + d0)      = o0;
    *(u16x8*)(dst + d0 + 8)  = o1;
    *(u16x8*)(dst + d0 + 64) = o2;
    *(u16x8*)(dst + d0 + 72) = o3;
  }

  #pragma unroll
  for (int r4 = 0; r4 < 4; ++r4) {
    int C = t + r4 * 256;
    int row = C >> 4, ch = C & 15;
    *(uint4*)(&vtile[row][ch * 8]) =
        *(const uint4*)(QKV + (size_t)(s0 + row) * QKV_N + 2 * DIM + h * HD + ch * 8);
  }
  __syncthreads();
  const int d = t >> 1;
  const int sc0 = (t & 1) * 32;
  u16* vdst = Vt + ((size_t)h * HD + d) * S_LEN + s0 + sc0;
  #pragma unroll
  for (int j = 0; j < 32; j += 8) {
    u16x8 v;
    #pragma unroll
    for (int e = 0; e < 8; ++e) v[e] = vtile[sc0 + j + e][d];
    *(u16x8*)(vdst + j) = v;
  }
}

// -------- flash attention: R4 staging (K+V LDS single-buf) + swapped-QK^T softmax
// QK^T computed as mfma(K,Q) -> S^T: lane(lq,lr) holds S[q=lr][k=nf*16+lq*4+r].
// Row softmax: in-register over 16 values + 2 shfl_xor (lanes 16,32).
// P packed to LDS as u16x4 (k=lq*4+0..3 contiguous). O-rescale alpha fetched
// per O-row (q=lq*4+r) via one bpermute per r.
__global__ __launch_bounds__(256) void attn_fwd(const u16* __restrict__ Qp,
                                                const u16* __restrict__ Kp,
                                                const u16* __restrict__ Vt,
                                                const int* __restrict__ cu,
                                                u16* __restrict__ Obf) {
  __shared__ u16 K_lds[64 * 128];    // [kv][d], chunk-swizzled
  __shared__ u16 VT_lds[128 * 64];   // [d][kv], chunk-swizzled
  __shared__ u16 P_lds[4][16 * 76];  // per-wave P[q][k], stride 76

  const int t = threadIdx.x;
  const int l = t & 63;
  const int w = t >> 6;
  const int lr = l & 15;
  const int lq = l >> 4;
  const int q0 = blockIdx.x * 64;
  const int h = blockIdx.y;

  int cs = 0, ce = S_LEN;
  #pragma unroll
  for (int b = 0; b < 4; ++b) {
    int lo = cu[b], hi = cu[b + 1];
    if (q0 >= lo && q0 < hi) { cs = lo; ce = hi; }
  }

  // Q fragment (B-operand of swapped QK^T): Q[q = q0+w*16+lr][d]
  const int qrow = q0 + w * 16 + lr;
  bf16x8 qf[4];
  const u16* qptr = Qp + ((size_t)h * S_LEN + qrow) * HD + lq * 8;
  #pragma unroll
  for (int ks = 0; ks < 4; ++ks) qf[ks] = *(const bf16x8*)(qptr + ks * 32);

  f32x4 acc_o[8];
  #pragma unroll
  for (int i = 0; i < 8; ++i) acc_o[i] = f32x4{0.f, 0.f, 0.f, 0.f};
  float m_run = -1e30f, l_run = 0.f;   // per-lane: row q = lr

  for (int kv0 = cs; kv0 < ce; kv0 += 64) {
    __syncthreads();
    {
      const u16* kbase = Kp + ((size_t)h * S_LEN + kv0) * HD;
      #pragma unroll
      for (int r4 = 0; r4 < 4; ++r4) {
        int C = t + r4 * 256;
        int row = C >> 4, ch = C & 15;
        int sch = (ch & 8) | ((ch ^ row) & 7);
        GLL16(kbase + row * HD + sch * 8, K_lds + (size_t)C * 8);
      }
      const u16* vbase = Vt + (size_t)h * HD * S_LEN + kv0;
      #pragma unroll
      for (int r4 = 0; r4 < 4; ++r4) {
        int C = t + r4 * 256;
        int row = C >> 3, ch = C & 7;
        int sch = (ch ^ row) & 7;
        GLL16(vbase + (size_t)row * S_LEN + sch * 8, VT_lds + (size_t)C * 8);
      }
    }
    __syncthreads();

    // S^T = K Q^T : s_acc[nf] reg r holds S[q=lr][k = nf*16 + lq*4 + r]
    f32x4 s_acc[4];
    __builtin_amdgcn_s_setprio(1);
    #pragma unroll
    for (int nf = 0; nf < 4; ++nf) {
      s_acc[nf] = f32x4{0.f, 0.f, 0.f, 0.f};
      int krow = nf * 16 + lr;   // A-frag row = k (lane lr), d-chunk = lq
      #pragma unroll
      for (int ks = 0; ks < 4; ++ks) {
        int ch = ks * 4 + lq;
        int sch = (ch & 8) | ((ch ^ krow) & 7);
        bf16x8 kf = *(const bf16x8*)(K_lds + krow * 128 + sch * 8);
        s_acc[nf] = __builtin_amdgcn_mfma_f32_16x16x32_bf16(kf, qf[ks], s_acc[nf], 0, 0, 0);
      }
    }
    __builtin_amdgcn_s_setprio(0);

    // in-register row softmax (q = lr), 16 k-values per lane
    float vmax = -1e30f;
    #pragma unroll
    for (int nf = 0; nf < 4; ++nf)
      #pragma unroll
      for (int r = 0; r < 4; ++r) vmax = fmaxf(vmax, s_acc[nf][r]);
    vmax = fmaxf(vmax, __shfl_xor(vmax, 16, 64));
    vmax = fmaxf(vmax, __shfl_xor(vmax, 32, 64));
    float mn = fmaxf(m_run, vmax);
    float alpha = __builtin_amdgcn_exp2f(m_run - mn);
    m_run = mn;
    float pv[4][4], sum = 0.f;
    #pragma unroll
    for (int nf = 0; nf < 4; ++nf)
      #pragma unroll
      for (int r = 0; r < 4; ++r) {
        float e = __builtin_amdgcn_exp2f(s_acc[nf][r] - mn);
        pv[nf][r] = e;
        sum += e;
      }
    sum += __shfl_xor(sum, 16, 64);
    sum += __shfl_xor(sum, 32, 64);
    l_run = l_run * alpha + sum;

    // rescale O: alpha for O-row q = lq*4+r lives at lane lq*16 + lq*4 + r
    float alphaO[4];
    #pragma unroll
    for (int r = 0; r < 4; ++r) alphaO[r] = __shfl(alpha, lq * 20 + r, 64);
    #pragma unroll
    for (int onf = 0; onf < 8; ++onf)
      #pragma unroll
      for (int r = 0; r < 4; ++r) acc_o[onf][r] *= alphaO[r];

    // P -> LDS: lane writes P[q=lr][k = nf*16 + lq*4 .. +3] as one b64
    u16* pl = P_lds[w];
    #pragma unroll
    for (int nf = 0; nf < 4; ++nf) {
      u16x4 pk;
      #pragma unroll
      for (int r = 0; r < 4; ++r) pk[r] = f2bf(pv[nf][r]);
      *(u16x4*)(pl + lr * 76 + nf * 16 + lq * 4) = pk;
    }

    // O += P V
    __builtin_amdgcn_s_setprio(1);
    #pragma unroll
    for (int ks = 0; ks < 2; ++ks) {
      bf16x8 pa = *(const bf16x8*)(pl + lr * 76 + ks * 32 + lq * 8);
      #pragma unroll
      for (int onf = 0; onf < 8; ++onf) {
        int d = onf * 16 + lr;
        int ch = ks * 4 + lq;
        int sch = (ch ^ d) & 7;
        bf16x8 vf = *(const bf16x8*)(VT_lds + d * 64 + sch * 8);
        acc_o[onf] = __builtin_amdgcn_mfma_f32_16x16x32_bf16(pa, vf, acc_o[onf], 0, 0, 0);
      }
    }
    __builtin_amdgcn_s_setprio(0);
  }

  // epilogue: inv for O-row q = lq*4+r fetched from lane lq*20+r
  float invO[4];
  #pragma unroll
  for (int r = 0; r < 4; ++r) invO[r] = 1.f / __shfl(l_run, lq * 20 + r, 64);
  #pragma unroll
  for (int r = 0; r < 4; ++r) {
    int srow = q0 + w * 16 + (lq << 2) + r;
    u16* orow = Obf + (size_t)srow * DIM + h * HD + lr;
    #pragma unroll
    for (int onf = 0; onf < 8; ++onf) orow[onf * 16] = f2bf(acc_o[onf][r] * invO[r]);
  }
}

extern "C" void kernel_launch(void* const* d_in, const int* in_sizes, int n_in,
                              void* d_out, int out_size, void* d_ws, size_t ws_size,
                              hipStream_t stream) {
  const float* hidden = (const float*)d_in[0];
  const float* cosb   = (const float*)d_in[1];
  const float* sinb   = (const float*)d_in[2];
  const float* qkv_w  = (const float*)d_in[3];
  const float* qkv_b  = (const float*)d_in[4];
  const float* proj_w = (const float*)d_in[5];
  const int*   cu     = (const int*)d_in[6];

  u16* Hbf   = (u16*)d_ws;
  u16* Wqkv  = Hbf   + (size_t)S_LEN * DIM;
  u16* Wproj = Wqkv  + (size_t)QKV_N * DIM;
  u16* QKVbf = Wproj + (size_t)DIM * DIM;
  u16* Kp    = QKVbf + (size_t)S_LEN * QKV_N;
  u16* Vt    = Kp    + (size_t)NH * S_LEN * HD;
  u16* Qp    = Wqkv;  // reuse: Wqkv dead after GEMM1
  u16* Abf   = Hbf;   // reuse: Hbf dead after GEMM1

  cvt_bf16_3<<<2048, 256, 0, stream>>>(hidden, Hbf, S_LEN * DIM / 4,
                                       qkv_w, Wqkv, QKV_N * DIM / 4,
                                       proj_w, Wproj, DIM * DIM / 4);

  gemm_bt_256<<<(S_LEN / 256) * (QKV_N / 256), 512, 0, stream>>>(
      Hbf, Wqkv, qkv_b, QKVbf, S_LEN, QKV_N, DIM);

  rope_pack<<<dim3(S_LEN / 64, NH), 256, 0, stream>>>(QKVbf, cosb, sinb, Qp, Kp, Vt);

  attn_fwd<<<dim3(S_LEN / 64, NH), 256, 0, stream>>>(Qp, Kp, Vt, cu, Abf);

  gemm_bt<false, true><<<dim3(DIM / 128, S_LEN / 128), 256, 0, stream>>>(
      Abf, Wproj, nullptr, d_out, S_LEN, DIM, DIM);
}